// Round 1
// baseline (3557.365 us; speedup 1.0000x reference)
//
#include <hip/hip_runtime.h>
#include <math.h>

#define IMG_H 256
#define IMG_W 256
#define IMG_SZ (IMG_H * IMG_W)
#define NP 49      /* C*p*p patch vector length */
#define HP 250     /* H - p + 1 */
#define KREF 64    /* refs per dim */
#define NB 4096    /* groups per image = 64*64 */
#define NCAND 1369 /* 37*37 */
#define VRAD 18
#define NIMG 2

// Map aligned-patch coordinates (253x253, after align_corners with s=4 on a
// 250x250 grid) to original patch coordinates. Returns false for inf slots.
__device__ __forceinline__ bool align_map(int r, int c, int& ro, int& co) {
    if (r < 0 || r > 252 || c < 0 || c > 252) return false;
    if (r == 252) {
        if (c == 252) { ro = 249; co = 249; return true; }
        if (c <= 248 && (c & 3) == 0) { ro = 249; co = c; return true; }
        return false;
    }
    if (c == 252) {
        if (r <= 248 && (r & 3) == 0) { ro = r; co = 249; return true; }
        return false;
    }
    if (r >= 250 || c >= 250) return false; // rows/cols 250,251 are pure pad
    if (r == 249) {
        if (c == 249) return false;          // corner swapped out
        if ((c & 3) == 0) return false;      // row-swap invalidated (c<=248 here)
        ro = 249; co = c; return true;
    }
    if (c == 249) {
        if ((r & 3) == 0) return false;
        ro = r; co = 249; return true;
    }
    ro = r; co = c; return true;
}

__global__ void zero_kernel(float* __restrict__ p, int total) {
    int i = blockIdx.x * blockDim.x + threadIdx.x;
    if (i < total) p[i] = 0.0f;
}

__global__ void div_kernel(const float* __restrict__ aN, const float* __restrict__ aW,
                           float* __restrict__ out, int total) {
    int i = blockIdx.x * blockDim.x + threadIdx.x;
    if (i < total) out[i] = aN[i] / aW[i];
}

// One block per reference patch. Computes 1369 candidate distances in the
// aligned coordinate space, then extracts M smallest (tie -> lower flat idx),
// exactly matching jax.lax.top_k on -dist with the center forced to -inf.
template <int M>
__global__ __launch_bounds__(256) void bm_kernel(const float* __restrict__ img,
                                                 int* __restrict__ idx_out) {
    __shared__ float refp[NP];
    __shared__ float dist[NCAND];
    __shared__ float bv[256];
    __shared__ int bi[256];
    const int ll = blockIdx.x, kk = blockIdx.y, n = blockIdx.z;
    const float* im = img + (size_t)n * IMG_SZ;
    const int t = threadIdx.x;
    const int rr = (kk < 63) ? 4 * kk : 249;  // row_ref
    const int cc = (ll < 63) ? 4 * ll : 249;  // col_ref
    if (t < NP) refp[t] = im[(rr + t / 7) * IMG_W + (cc + t % 7)];
    __syncthreads();
    const int ar0 = 4 * kk, ac0 = 4 * ll;  // aligned ref position
    for (int cand = t; cand < NCAND; cand += 256) {
        const int dr = cand / 37 - VRAD, dc = cand % 37 - VRAD;
        int ro, co;
        float d;
        if (align_map(ar0 + dr, ac0 + dc, ro, co)) {
            const float* base = im + ro * IMG_W + co;
            float s = 0.f;
#pragma unroll
            for (int ki = 0; ki < 7; ++ki)
#pragma unroll
                for (int kj = 0; kj < 7; ++kj) {
                    float df = base[ki * IMG_W + kj] - refp[ki * 7 + kj] + 1e-6f;
                    s = fmaf(df, df, s);
                }
            d = sqrtf(s);
        } else {
            d = INFINITY;
        }
        dist[cand] = d;
    }
    __syncthreads();
    if (t == 0) dist[VRAD * 37 + VRAD] = -1.0f;  // center: always first (all real dists >= 0)
    __syncthreads();
    int* out = idx_out + (size_t)((n * KREF + kk) * KREF + ll) * M;
    for (int sel = 0; sel < M; ++sel) {
        float mv = INFINITY;
        int mi = NCAND;
        for (int cand = t; cand < NCAND; cand += 256) {
            float v = dist[cand];
            if (v < mv || (v == mv && cand < mi)) { mv = v; mi = cand; }
        }
        bv[t] = mv;
        bi[t] = mi;
        __syncthreads();
        for (int off = 128; off > 0; off >>= 1) {
            if (t < off) {
                float v2 = bv[t + off];
                int j2 = bi[t + off];
                if (v2 < bv[t] || (v2 == bv[t] && j2 < bi[t])) { bv[t] = v2; bi[t] = j2; }
            }
            __syncthreads();
        }
        if (t == 0) {
            int win = bi[0];
            int dr = win / 37 - VRAD, dc = win % 37 - VRAD;
            int ir = min(rr + dr, 249);
            int ic = min(cc + dc, 249);
            out[sel] = ir * HP + ic;
            dist[win] = INFINITY;
        }
        __syncthreads();
    }
}

// One wave (64 threads) per group. ROUND2=false: Gram from Y, A=G, B=G-n*s^2*I.
// ROUND2=true: Gram from X (den1 patches), A=G+n*s^2*I, B=G. Then
// theta = A^-1 B via Cholesky, X_hat = theta*Y, w = 1/clip(rowsum(theta^2),1/M,1),
// fused scatter-aggregation via atomics.
template <int M, bool ROUND2>
__global__ __launch_bounds__(64) void denoise_kernel(
    const float* __restrict__ y, const float* __restrict__ xsrc,
    const int* __restrict__ idx, const float* __restrict__ sigma_p,
    float* __restrict__ accN, float* __restrict__ accW) {
    constexpr int XR = ROUND2 ? M : 1;
    __shared__ float Ys[M][NP];
    __shared__ float Xs[XR][NP];
    __shared__ float A[M][M];
    __shared__ float B[M][M + 1];
    __shared__ float wsh[M];
    const int b = blockIdx.x, n = blockIdx.y;
    const int t = threadIdx.x;
    const int* gidx = idx + (size_t)(n * NB + b) * M;
    const float* im = y + (size_t)n * IMG_SZ;
    const float* xim = xsrc + (size_t)n * IMG_SZ;
    for (int e = t; e < M * NP; e += 64) {
        int i = e / NP, ch = e % NP;
        int p = gidx[i];
        int off = (p / HP + ch / 7) * IMG_W + (p % HP + ch % 7);
        Ys[i][ch] = im[off];
        if (ROUND2) Xs[i][ch] = xim[off];
    }
    __syncthreads();
    const float sg = sigma_p[0];
    const float ns2 = 49.f * sg * sg;
    for (int e = t; e < M * M; e += 64) {
        int i = e / M, j = e % M;
        const float* Pi = ROUND2 ? Xs[i] : Ys[i];
        const float* Pj = ROUND2 ? Xs[j] : Ys[j];
        float s = 0.f;
        for (int k = 0; k < NP; ++k) s = fmaf(Pi[k], Pj[k], s);
        A[i][j] = (ROUND2 && i == j) ? s + ns2 : s;
        B[i][j] = (!ROUND2 && i == j) ? s - ns2 : s;
    }
    __syncthreads();
    // Cholesky, lower triangle in place in A
    for (int k = 0; k < M; ++k) {
        if (t == 0) A[k][k] = sqrtf(A[k][k]);
        __syncthreads();
        if (t > k && t < M) A[t][k] = A[t][k] / A[k][k];
        __syncthreads();
        if (t > k && t < M) {
            float lik = A[t][k];
            for (int j = k + 1; j <= t; ++j) A[t][j] = fmaf(-lik, A[j][k], A[t][j]);
        }
        __syncthreads();
    }
    // Solve A*theta = B in place in B; lane t owns column t
    if (t < M) {
        for (int i = 0; i < M; ++i) {
            float s = B[i][t];
            for (int j = 0; j < i; ++j) s = fmaf(-A[i][j], B[j][t], s);
            B[i][t] = s / A[i][i];
        }
        for (int i = M - 1; i >= 0; --i) {
            float s = B[i][t];
            for (int j = i + 1; j < M; ++j) s = fmaf(-A[j][i], B[j][t], s);
            B[i][t] = s / A[i][i];
        }
    }
    __syncthreads();
    if (t < M) {
        float s = 0.f;
        for (int j = 0; j < M; ++j) { float th = B[t][j]; s = fmaf(th, th, s); }
        s = fminf(fmaxf(s, 1.0f / (float)M), 1.0f);
        wsh[t] = 1.0f / s;
    }
    __syncthreads();
    float* aN = accN + (size_t)n * IMG_SZ;
    float* aW = accW + (size_t)n * IMG_SZ;
    for (int e = t; e < M * NP; e += 64) {
        int i = e / NP, ch = e % NP;
        float s = 0.f;
        for (int j = 0; j < M; ++j) s = fmaf(B[i][j], Ys[j][ch], s);
        float wi = wsh[i];
        int p = gidx[i];
        int r = p / HP + ch / 7, c = p % HP + ch % 7;
        atomicAdd(&aN[r * IMG_W + c], s * wi);
        atomicAdd(&aW[r * IMG_W + c], wi);
    }
}

extern "C" void kernel_launch(void* const* d_in, const int* in_sizes, int n_in,
                              void* d_out, int out_size, void* d_ws, size_t ws_size,
                              hipStream_t stream) {
    const float* y = (const float*)d_in[0];
    const float* sigma = (const float*)d_in[1];
    float* out = (float*)d_out;

    char* ws = (char*)d_ws;
    size_t off = 0;
    auto carve = [&](size_t bytes) {
        void* p = ws + off;
        off += (bytes + 255) & ~(size_t)255;
        return p;
    };
    int* idx1 = (int*)carve((size_t)NIMG * NB * 18 * sizeof(int));
    int* idx2 = (int*)carve((size_t)NIMG * NB * 55 * sizeof(int));
    float* accs = (float*)carve((size_t)4 * NIMG * IMG_SZ * sizeof(float));
    float* den1 = (float*)carve((size_t)NIMG * IMG_SZ * sizeof(float));
    float* accN1 = accs;
    float* accW1 = accs + (size_t)NIMG * IMG_SZ;
    float* accN2 = accs + (size_t)2 * NIMG * IMG_SZ;
    float* accW2 = accs + (size_t)3 * NIMG * IMG_SZ;

    const int accTotal = 4 * NIMG * IMG_SZ;
    zero_kernel<<<(accTotal + 255) / 256, 256, 0, stream>>>(accs, accTotal);

    // Round 1: M1=18, P1=7
    bm_kernel<18><<<dim3(KREF, KREF, NIMG), 256, 0, stream>>>(y, idx1);
    denoise_kernel<18, false><<<dim3(NB, NIMG), 64, 0, stream>>>(y, y, idx1, sigma, accN1, accW1);
    div_kernel<<<(NIMG * IMG_SZ + 255) / 256, 256, 0, stream>>>(accN1, accW1, den1, NIMG * IMG_SZ);

    // Round 2: M2=55, P2=7
    bm_kernel<55><<<dim3(KREF, KREF, NIMG), 256, 0, stream>>>(den1, idx2);
    denoise_kernel<55, true><<<dim3(NB, NIMG), 64, 0, stream>>>(y, den1, idx2, sigma, accN2, accW2);
    div_kernel<<<(NIMG * IMG_SZ + 255) / 256, 256, 0, stream>>>(accN2, accW2, out, NIMG * IMG_SZ);
}